// Round 2
// baseline (1407.607 us; speedup 1.0000x reference)
//
#include <hip/hip_runtime.h>

#define NSTEP 2047
#define NLANE 1024   // threads total
#define SPL   4      // samples per lane: NLANE*SPL = 4096

__device__ __forceinline__ float fexp2(float x) {
    float r; asm("v_exp_f32 %0, %1" : "=v"(r) : "v"(x)); return r;
}
__device__ __forceinline__ float frcp(float x) {
    float r; asm("v_rcp_f32 %0, %1" : "=v"(r) : "v"(x)); return r;
}

__global__ __launch_bounds__(64, 1)
void cstr_kernel(const float* __restrict__ w, const float* __restrict__ Kp,
                 const float* __restrict__ Lp, const float* __restrict__ Mp,
                 const float* __restrict__ Mop, float* __restrict__ out)
{
    const int lane = blockIdx.x * 64 + threadIdx.x;   // 0..1023

    // Uniform parameters.
    const float K0 = Kp[0], K1 = Kp[1];
    const float m0 = Mp[0], m1 = Mp[1], m2 = Mp[2], m3 = Mp[3];
    const float MoV = Mop[0];
    const float c00 = Lp[0];
    const float c01 = Lp[1] + Lp[4];
    const float c02 = Lp[2] + Lp[8];
    const float c03 = Lp[3] + Lp[12];
    const float c11 = Lp[5];
    const float c12 = Lp[6] + Lp[9];
    const float c13 = Lp[7] + Lp[13];
    const float c22 = Lp[10];
    const float c23 = Lp[11] + Lp[14];
    const float c33 = Lp[15];

    constexpr float Hc  = 0.01f;
    constexpr float Acf = 1.0f - Hc;
    constexpr float Bcf = -0.5f * Hc * Hc;
    constexpr float T2L = 2.8853900817779268f;  // 2*log2(e)
    constexpr float L2E = 1.4426950408889634f;  // log2(e)
    constexpr float SC1 = 0.5f * Hc;
    constexpr float SC2 = Hc * Hc / 3.0f;
    constexpr float HH  = 0.5f * Hc;

    const float* r0[SPL]; const float* r1[SPL];
    float x1[SPL], x2[SPL], xh1[SPL], xh2[SPL], u[SPL];
    float sxx[SPL], suu[SPL], sd[SPL];

#pragma unroll
    for (int s = 0; s < SPL; ++s) {
        r0[s] = w + (size_t)(lane + NLANE * s) * (2 * NSTEP);
        r1[s] = r0[s] + NSTEP;
    }

    // ---- t = 0: delta forced to 1, xhat = x0 = (1,0), u = K0 ----
    const float Ec  = fexp2(T2L);
    const float t1c = 1.0f - 2.0f * frcp(Ec + 1.0f);   // tanh(1)
#pragma unroll
    for (int s = 0; s < SPL; ++s) {
        u[s]   = K0;
        x1[s]  = Acf + Hc * SC1 + Hc * K0 + r0[s][0];
        x2[s]  = Bcf - Hc * t1c + HH * K0 + r1[s][0];
        xh1[s] = 1.0f; xh2[s] = 0.0f;
        sxx[s] = 1.0f; suu[s] = K0 * K0; sd[s] = 1.0f;
    }

    // One scalar step; all state by reference so unrolled callers keep
    // compile-time indexing (no scratch).
    auto step = [&](float& X1, float& X2, float& XH1, float& XH2, float& U,
                    float& SXX, float& SUU, float& SD,
                    float w1, float w2, bool acc) {
        // fprev = f(xhat_prev, u_prev)
        const float Eh1 = fexp2(XH1 * T2L);
        const float th1 = 1.0f - 2.0f * frcp(Eh1 + 1.0f);
        const float Eh2 = fexp2(XH2 * T2L);
        const float th2 = 1.0f - 2.0f * frcp(Eh2 + 1.0f);
        const float sh2 = 1.0f - th2 * th2;
        const float Sh2 = th2 + sh2 * (SC1 - SC2 * th2);
        const float f1 = Acf * XH1 + Hc * (Sh2 + U);
        const float f2 = Acf * XH2 + Bcf - Hc * th1 + HH * U;
        // x-side tanh (independent chain)
        const float Ex1 = fexp2(X1 * T2L);
        const float tx1 = 1.0f - 2.0f * frcp(Ex1 + 1.0f);
        const float Ex2 = fexp2(X2 * T2L);
        const float tx2 = 1.0f - 2.0f * frcp(Ex2 + 1.0f);
        const float sx2 = 1.0f - tx2 * tx2;
        const float Sx2 = tx2 + sx2 * (SC1 - SC2 * tx2);
        // phi = rx.L.rx + M.rx + Mo, rx = (x1,x2,f1,f2)
        const float g1 = m0 + c00 * X1 + c01 * X2 + c02 * f1 + c03 * f2;
        const float g2 = m1 + c11 * X2 + c12 * f1 + c13 * f2;
        const float g3 = m2 + c22 * f1 + c23 * f2;
        const float g4 = m3 + c33 * f2;
        const float phi = MoV + X1 * g1 + X2 * g2 + f1 * g3 + f2 * g4;
        const float delta = frcp(1.0f + fexp2(-phi * L2E));
        // xhat, u
        const float nh1 = f1 + delta * (X1 - f1);
        const float nh2 = f2 + delta * (X2 - f2);
        const float un  = K0 * nh1 + K1 * nh2;
        if (acc) {
            SXX += X1 * X1 + X2 * X2;
            const float us = K0 * X1 + K1 * X2;
            SUU += us * us;
            SD  += delta;
        }
        const float nx1 = Acf * X1 + Hc * (Sx2 + un) + w1;
        const float nx2 = Acf * X2 + Bcf - Hc * tx1 + HH * un + w2;
        X1 = nx1; X2 = nx2; XH1 = nh1; XH2 = nh2; U = un;
    };

#define STEP(s, a, b, acc) step(x1[s], x2[s], xh1[s], xh2[s], u[s], sxx[s], suu[s], sd[s], (a), (b), (acc))

    // t = 1
#pragma unroll
    for (int s = 0; s < SPL; ++s) STEP(s, r0[s][1], r1[s][1], true);

    // t = 2 .. 2045: 511 groups of 4, prefetched one group ahead.
    float cw0[SPL][4], cw1[SPL][4], nw0[SPL][4], nw1[SPL][4];
#pragma unroll
    for (int s = 0; s < SPL; ++s)
#pragma unroll
        for (int k = 0; k < 4; ++k) { cw0[s][k] = r0[s][2 + k]; cw1[s][k] = r1[s][2 + k]; }

    for (int g = 0; g < 511; ++g) {
        const int tn = (g < 510) ? (6 + 4 * g) : 2;   // last prefetch clamps to a safe addr
#pragma unroll
        for (int s = 0; s < SPL; ++s)
#pragma unroll
            for (int k = 0; k < 4; ++k) { nw0[s][k] = r0[s][tn + k]; nw1[s][k] = r1[s][tn + k]; }
#pragma unroll
        for (int k = 0; k < 4; ++k)
#pragma unroll
            for (int s = 0; s < SPL; ++s) STEP(s, cw0[s][k], cw1[s][k], true);
#pragma unroll
        for (int s = 0; s < SPL; ++s)
#pragma unroll
            for (int k = 0; k < 4; ++k) { cw0[s][k] = nw0[s][k]; cw1[s][k] = nw1[s][k]; }
    }

    // t = 2046: final step, no stage accumulation.
#pragma unroll
    for (int s = 0; s < SPL; ++s) STEP(s, r0[s][2046], r1[s][2046], false);

#pragma unroll
    for (int s = 0; s < SPL; ++s)
        out[lane + NLANE * s] = sxx[s] + suu[s] + sd[s]
                              + 10.0f * (x1[s] * x1[s] + x2[s] * x2[s]);
#undef STEP
}

extern "C" void kernel_launch(void* const* d_in, const int* in_sizes, int n_in,
                              void* d_out, int out_size, void* d_ws, size_t ws_size,
                              hipStream_t stream) {
    const float* w  = (const float*)d_in[0];
    const float* K  = (const float*)d_in[1];
    const float* L  = (const float*)d_in[2];
    const float* M  = (const float*)d_in[3];
    const float* Mo = (const float*)d_in[4];
    float* out = (float*)d_out;
    cstr_kernel<<<dim3(NLANE / 64), dim3(64), 0, stream>>>(w, K, L, M, Mo, out);
}

// Round 3
// 277.377 us; speedup vs baseline: 5.0747x; 5.0747x over previous
//
#include <hip/hip_runtime.h>

#define NSTEP 2047

typedef float v2f  __attribute__((ext_vector_type(2)));
typedef float v2fu __attribute__((ext_vector_type(2), aligned(4)));  // 4B-safe load

__device__ __forceinline__ float fexp2(float x) {
    float r; asm("v_exp_f32 %0, %1" : "=v"(r) : "v"(x)); return r;
}
__device__ __forceinline__ float frcp(float x) {
    float r; asm("v_rcp_f32 %0, %1" : "=v"(r) : "v"(x)); return r;
}

__global__ __launch_bounds__(64, 1)
void cstr_kernel(const float* __restrict__ w, const float* __restrict__ Kp,
                 const float* __restrict__ Lp, const float* __restrict__ Mp,
                 const float* __restrict__ Mop, float* __restrict__ out)
{
    const int lane = blockIdx.x * 64 + threadIdx.x;   // 0..4095

    const float K0 = Kp[0], K1 = Kp[1];
    const float MoV = Mop[0];
    // Symmetrized quadratic form, arranged as packed column vectors:
    // G12 = (m0,m1) + (c00,0)x1 + (c01,c11)x2 + (c02,c12)f1 + (c03,c13)f2
    // G34 = (m2,m3) + (c22,0)f1 + (c23,c33)f2
    const v2f Mv  = {Mp[0], Mp[1]};
    const v2f Mv2 = {Mp[2], Mp[3]};
    const v2f C0  = {Lp[0],          0.0f};
    const v2f C1  = {Lp[1] + Lp[4],  Lp[5]};
    const v2f C2  = {Lp[2] + Lp[8],  Lp[6] + Lp[9]};
    const v2f C3  = {Lp[3] + Lp[12], Lp[7] + Lp[13]};
    const v2f D0  = {Lp[10],         0.0f};
    const v2f D1  = {Lp[11] + Lp[14], Lp[15]};

    constexpr float Hc  = 0.01f;
    constexpr float Acf = 1.0f - Hc;
    constexpr float Bcf = -0.5f * Hc * Hc;
    constexpr float T2L = 2.8853900817779268f;  // 2*log2(e)
    constexpr float L2E = 1.4426950408889634f;  // log2(e)
    constexpr float SC1 = 0.5f * Hc;            // H/2 (S-shift)
    constexpr float HH  = 0.5f * Hc;

    const float* r0 = w + (size_t)lane * (2 * NSTEP);  // w[b,0,:]
    const float* r1 = r0 + NSTEP;                      // w[b,1,:]

    v2f X, XH;
    float U, SUU, SD;
    v2f SXX;

    // Prologue loads (issued early; latency amortized once).
    const float w1_0 = r0[0],    w2_0 = r1[0];
    const float w1_1 = r0[1],    w2_1 = r1[1];
    const float w1_T = r0[2046], w2_T = r1[2046];

    // ---- t = 0: delta forced to 1, xhat = x0 = (1,0), u = K0 ----
    {
        const float E  = fexp2(T2L);                    // exp(2*1)
        const float t1 = 1.0f - 2.0f * frcp(E + 1.0f);  // tanh(1)
        U = K0;
        X.x = Acf + Hc * SC1 + Hc * K0 + w1_0;          // S(0) = H/2 exactly (to O(H^3))
        X.y = Bcf - Hc * t1 + HH * K0 + w2_0;
        XH = (v2f){1.0f, 0.0f};
        SXX = (v2f){1.0f, 0.0f};
        SUU = K0 * K0;
        SD  = 1.0f;
    }

    auto step = [&](float w1, float w2, bool acc) {
        // tanh pair for xhat: need (tanh(xh1), S(xh2)) with S(v)=tanh(v+H/2)+O(4e-6)
        v2f Ph = XH; Ph.y += SC1;
        v2f Px = X;  Px.y += SC1;
        v2f Ah = Ph * T2L;
        v2f Ax = Px * T2L;
        v2f Eh, Ex;
        Eh.x = fexp2(Ah.x); Eh.y = fexp2(Ah.y);
        Ex.x = fexp2(Ax.x); Ex.y = fexp2(Ax.y);
        v2f Dh = Eh + 1.0f;
        v2f Dx = Ex + 1.0f;
        v2f Rh, Rx;
        Rh.x = frcp(Dh.x); Rh.y = frcp(Dh.y);
        Rx.x = frcp(Dx.x); Rx.y = frcp(Dx.y);
        v2f Th = 1.0f - 2.0f * Rh;   // (tanh(xh1), S(xh2))
        v2f Tx = 1.0f - 2.0f * Rx;   // (tanh(x1),  S(x2))
        // fprev = f(xhat_prev, u_prev)
        const float f1 = Acf * XH.x + Hc * (Th.y + U);
        const float f2 = Acf * XH.y + (Bcf + HH * U) - Hc * Th.x;
        const v2f F = {f1, f2};
        // phi
        v2f G12 = Mv + C0 * X.x + C1 * X.y + C2 * f1 + C3 * f2;
        v2f G34 = Mv2 + D0 * f1 + D1 * f2;
        v2f PP  = X * G12 + F * G34;
        const float phi = MoV + PP.x + PP.y;
        const float delta = frcp(1.0f + fexp2(phi * -L2E));
        // xhat, u
        const v2f NH = F + delta * (X - F);
        const float un = K0 * NH.x + K1 * NH.y;
        if (acc) {
            SXX += X * X;
            const float us = K0 * X.x + K1 * X.y;
            SUU += us * us;
            SD  += delta;
        }
        // x update (u linear in f)
        const float nx1 = Acf * X.x + Hc * (Tx.y + un) + w1;
        const float nx2 = Acf * X.y + (Bcf + HH * un) - Hc * Tx.x + w2;
        X = (v2f){nx1, nx2};
        XH = NH; U = un;
    };

    // t = 1
    step(w1_1, w2_1, true);

    // t = 2 .. 2045: 511 groups of 4; unroll-2 role-swapped double buffer
    // (no register rotation copies). Group g covers t = 2+4g.
    v2fu a0, a1, b0, b1;      // buffer A
    v2fu na0, na1, nb0, nb1;  // buffer B
    a0 = *(const v2fu*)(r0 + 2); a1 = *(const v2fu*)(r0 + 4);
    b0 = *(const v2fu*)(r1 + 2); b1 = *(const v2fu*)(r1 + 4);

    const float* p0 = r0 + 6;   // next group's row0
    const float* p1 = r1 + 6;

    for (int k = 0; k < 255; ++k) {
        // prefetch group 2k+1 into B
        na0 = *(const v2fu*)(p0);     na1 = *(const v2fu*)(p0 + 2);
        nb0 = *(const v2fu*)(p1);     nb1 = *(const v2fu*)(p1 + 2);
        // compute group 2k from A
        step(a0.x, b0.x, true); step(a0.y, b0.y, true);
        step(a1.x, b1.x, true); step(a1.y, b1.y, true);
        // prefetch group 2k+2 into A (k=254 -> group 510, valid: t=2042..2045)
        a0 = *(const v2fu*)(p0 + 4);  a1 = *(const v2fu*)(p0 + 6);
        b0 = *(const v2fu*)(p1 + 4);  b1 = *(const v2fu*)(p1 + 6);
        // compute group 2k+1 from B
        step(na0.x, nb0.x, true); step(na0.y, nb0.y, true);
        step(na1.x, nb1.x, true); step(na1.y, nb1.y, true);
        p0 += 8; p1 += 8;
    }
    // group 510 (t = 2042..2045) sits in A
    step(a0.x, b0.x, true); step(a0.y, b0.y, true);
    step(a1.x, b1.x, true); step(a1.y, b1.y, true);

    // t = 2046: final step, no stage accumulation
    step(w1_T, w2_T, false);

    out[lane] = SXX.x + SXX.y + SUU + SD + 10.0f * (X.x * X.x + X.y * X.y);
}

extern "C" void kernel_launch(void* const* d_in, const int* in_sizes, int n_in,
                              void* d_out, int out_size, void* d_ws, size_t ws_size,
                              hipStream_t stream) {
    const float* w  = (const float*)d_in[0];
    const float* K  = (const float*)d_in[1];
    const float* L  = (const float*)d_in[2];
    const float* M  = (const float*)d_in[3];
    const float* Mo = (const float*)d_in[4];
    float* out = (float*)d_out;
    cstr_kernel<<<dim3(4096 / 64), dim3(64), 0, stream>>>(w, K, L, M, Mo, out);
}

// Round 4
// 238.633 us; speedup vs baseline: 5.8986x; 1.1624x over previous
//
#include <hip/hip_runtime.h>

#define NSTEP 2047
#define NB    4096

__device__ __forceinline__ float fexp2(float x) {
    float r; asm("v_exp_f32 %0, %1" : "=v"(r) : "v"(x)); return r;
}
__device__ __forceinline__ float frcp(float x) {
    float r; asm("v_rcp_f32 %0, %1" : "=v"(r) : "v"(x)); return r;
}
// Swap within lane pair (0<->1, 2<->3, ...): DPP quad_perm [1,0,3,2].
__device__ __forceinline__ float pswap(float x) {
#if __has_builtin(__builtin_amdgcn_mov_dpp)
    int i = __builtin_bit_cast(int, x);
    i = __builtin_amdgcn_mov_dpp(i, 0xB1, 0xF, 0xF, true);
    return __builtin_bit_cast(float, i);
#else
    return __shfl_xor(x, 1, 64);
#endif
}

__global__ __launch_bounds__(64, 1)
void cstr_kernel(const float* __restrict__ w, const float* __restrict__ Kp,
                 const float* __restrict__ Lp, const float* __restrict__ Mp,
                 const float* __restrict__ Mop, float* __restrict__ out)
{
    const int tid = blockIdx.x * 64 + threadIdx.x;   // 0..8191
    const int par = tid & 1;                         // 0: component 1, 1: component 2
    const int b   = tid >> 1;                        // sample index

    constexpr float Hc  = 0.01f;
    constexpr float Acf = 1.0f - Hc;
    constexpr float Bcf = -0.5f * Hc * Hc;
    constexpr float T2L = 2.8853900817779268f;  // 2*log2(e)
    constexpr float L2E = 1.4426950408889634f;  // log2(e)
    constexpr float SC1 = 0.5f * Hc;            // H/2 tanh shift (RK stage identity)
    constexpr float HH  = 0.5f * Hc;

    // Uniform scalars.
    const float K0 = Kp[0], K1 = Kp[1];
    const float MoV = Mop[0];
    // Symmetrized A = (L + L^T)/2 over rx = (x1, x2, f1, f2).
    float A[4][4];
#pragma unroll
    for (int i = 0; i < 4; ++i)
#pragma unroll
        for (int j = 0; j < 4; ++j)
            A[i][j] = 0.5f * (Lp[i * 4 + j] + Lp[j * 4 + i]);

    // ---- per-lane parity constants (VGPR, selected once) ----
    const float cK   = par ? K1 : K0;               // own K component
    const float cTf  = par ? -Hc : Hc;              // coef of partner tanh
    const float cUf  = par ? HH : Hc;               // coef of u
    const float c0f  = par ? Bcf : 0.0f;            // additive const
    const float cShT = par ? (SC1 * T2L) : 0.0f;    // tanh input shift, pre-scaled
    // phi rows: own x-row (h_a) and own f-row (h_b), coeffs ordered (x_own, x_p, f_own, f_p)
    const float aXo = par ? A[1][1] : A[0][0];
    const float aXp = par ? A[1][0] : A[0][1];
    const float aFo = par ? A[1][3] : A[0][2];
    const float aFp = par ? A[1][2] : A[0][3];
    const float am  = par ? Mp[1]   : Mp[0];
    const float bXo = par ? A[3][1] : A[2][0];
    const float bXp = par ? A[3][0] : A[2][1];
    const float bFo = par ? A[3][3] : A[2][2];
    const float bFp = par ? A[3][2] : A[2][3];
    const float bm  = par ? Mp[3]   : Mp[2];

    // own disturbance row: w[b, par, :]
    const float* rw = w + (size_t)b * (2 * NSTEP) + (size_t)par * NSTEP;

    // Prologue loads.
    const float w_0 = rw[0];
    const float w_1 = rw[1];
    const float w_T = rw[2046];

    // ---- t = 0: delta = 1, xhat = x0 = (1,0), u = K0 ----
    const float E1 = fexp2(T2L);
    const float tanh1 = 1.0f - 2.0f * frcp(E1 + 1.0f);
    float X  = (par ? (Bcf - Hc * tanh1 + HH * K0)
                    : (Acf + Hc * SC1 + Hc * K0)) + w_0;
    float XH = par ? 0.0f : 1.0f;
    float U  = K0;
    float SXX = par ? 0.0f : 1.0f;
    float SUU = K0 * K0;   // duplicated on both lanes
    float SD  = 1.0f;      // duplicated

    auto step = [&](float wi, bool acc) {
        // own tanh evals: even lane tanh(v), odd lane tanh(v + H/2) = S(v)
        const float eh = fexp2(XH * T2L + cShT);
        const float th_h = 1.0f - 2.0f * frcp(eh + 1.0f);
        const float ex = fexp2(X * T2L + cShT);
        const float th_x = 1.0f - 2.0f * frcp(ex + 1.0f);
        const float tp_h = pswap(th_h);   // partner's xh-tanh
        // fprev component: even f1 = .99xh1 + H*S(xh2) + H*u
        //                  odd  f2 = .99xh2 - H*tanh(xh1) + H/2*u - H^2/2
        const float F = Acf * XH + (cTf * tp_h + (cUf * U + c0f));
        // phi = rx^T A rx + m.rx + Mo, split by rows
        const float Xp = pswap(X);
        const float Fp = pswap(F);
        const float h_a = am + aXo * X + aXp * Xp + aFo * F + aFp * Fp;
        const float h_b = bm + bXo * X + bXp * Xp + bFo * F + bFp * Fp;
        const float part = X * h_a + F * h_b;
        const float phi = (part + pswap(part)) + MoV;
        const float delta = frcp(1.0f + fexp2(phi * -L2E));   // sigmoid (duplicated)
        // xhat, u
        const float NH = F + delta * (X - F);
        const float tK = cK * NH;
        const float Un = tK + pswap(tK);
        if (acc) {
            SXX += X * X;
            const float tS = cK * X;
            const float us = tS + pswap(tS);
            SUU += us * us;
            SD  += delta;
        }
        // x update, using partner's x-tanh
        const float tp_x = pswap(th_x);
        X  = Acf * X + (cTf * tp_x + (cUf * Un + (c0f + wi)));
        XH = NH;
        U  = Un;
    };

    // t = 1
    step(w_1, true);

    // t = 2 .. 2045: 511 groups of 4; unroll-2 role-swapped double buffer.
    float c0 = rw[2], c1 = rw[3], c2 = rw[4], c3 = rw[5];
    float n0, n1, n2, n3;
    const float* p = rw + 6;
    for (int k = 0; k < 255; ++k) {
        n0 = p[0]; n1 = p[1]; n2 = p[2]; n3 = p[3];      // group 2k+1
        step(c0, true); step(c1, true); step(c2, true); step(c3, true);   // group 2k
        c0 = p[4]; c1 = p[5]; c2 = p[6]; c3 = p[7];      // group 2k+2
        step(n0, true); step(n1, true); step(n2, true); step(n3, true);   // group 2k+1
        p += 8;
    }
    // group 510: t = 2042..2045
    step(c0, true); step(c1, true); step(c2, true); step(c3, true);

    // t = 2046: no stage accumulation
    step(w_T, false);

    // out[b] = sum_x x.x + sum_u u^2 + sum delta + 10 * xT.xT
    const float xx = X * X;
    const float fin = (SXX + pswap(SXX)) + SUU + SD + 10.0f * (xx + pswap(xx));
    if (par == 0) out[b] = fin;
}

extern "C" void kernel_launch(void* const* d_in, const int* in_sizes, int n_in,
                              void* d_out, int out_size, void* d_ws, size_t ws_size,
                              hipStream_t stream) {
    const float* w  = (const float*)d_in[0];
    const float* K  = (const float*)d_in[1];
    const float* L  = (const float*)d_in[2];
    const float* M  = (const float*)d_in[3];
    const float* Mo = (const float*)d_in[4];
    float* out = (float*)d_out;
    cstr_kernel<<<dim3(2 * NB / 64), dim3(64), 0, stream>>>(w, K, L, M, Mo, out);
}

// Round 5
// 202.719 us; speedup vs baseline: 6.9436x; 1.1772x over previous
//
#include <hip/hip_runtime.h>

#define NSTEP 2047
#define NB    4096

__device__ __forceinline__ float fexp2(float x) {
    float r; asm("v_exp_f32 %0, %1" : "=v"(r) : "v"(x)); return r;
}
__device__ __forceinline__ float frcp(float x) {
    float r; asm("v_rcp_f32 %0, %1" : "=v"(r) : "v"(x)); return r;
}
// quad_perm DPP: lane l reads lane sel[l] of its quad. CTRL = p0|p1<<2|p2<<4|p3<<6.
template <int CTRL>
__device__ __forceinline__ float qperm(float x) {
    int i = __builtin_bit_cast(int, x);
    i = __builtin_amdgcn_mov_dpp(i, CTRL, 0xF, 0xF, true);
    return __builtin_bit_cast(float, i);
}
#define XOR1 0xB1  // [1,0,3,2]
#define XOR2 0x4E  // [2,3,0,1]
#define ROT1 0x39  // [1,2,3,0] : lane l <- l+1
#define ROT3 0x93  // [3,0,1,2] : lane l <- l-1

__global__ __launch_bounds__(64, 1)
void cstr_kernel(const float* __restrict__ w, const float* __restrict__ Kp,
                 const float* __restrict__ Lp, const float* __restrict__ Mp,
                 const float* __restrict__ Mop, float* __restrict__ out)
{
    const int tid = blockIdx.x * 64 + threadIdx.x;   // 0..16383
    const int q   = tid & 3;                         // quad lane: owns rx[q]
    const int b   = tid >> 2;                        // sample

    constexpr float Hc  = 0.01f;
    constexpr float Acf = 1.0f - Hc;
    constexpr float Bcf = -0.5f * Hc * Hc;
    constexpr float T2L = 2.8853900817779268f;  // 2*log2(e)
    constexpr float L2E = 1.4426950408889634f;  // log2(e)
    constexpr float SC1 = 0.5f * Hc;            // H/2 tanh shift
    constexpr float HH  = 0.5f * Hc;

    const float K0 = Kp[0], K1 = Kp[1], MoV = Mop[0];
    const float sigBias = -MoV * L2E;

    // symmetrized A = (L+L^T)/2, scalar names (compile-time indexed only)
    const float A00 = Lp[0], A11 = Lp[5], A22 = Lp[10], A33 = Lp[15];
    const float A01 = 0.5f * (Lp[1]  + Lp[4]);
    const float A02 = 0.5f * (Lp[2]  + Lp[8]);
    const float A03 = 0.5f * (Lp[3]  + Lp[12]);
    const float A12 = 0.5f * (Lp[6]  + Lp[9]);
    const float A13 = 0.5f * (Lp[7]  + Lp[13]);
    const float A23 = 0.5f * (Lp[11] + Lp[14]);

    const bool odd = (q & 1) != 0;
    const bool hi  = (q & 2) != 0;
    // per-lane constants
    const float cTf    = odd ? -Hc : Hc;         // coeff of partner tanh
    const float cUf    = odd ? HH  : Hc;         // coeff of u
    const float c0f    = odd ? Bcf : 0.0f;       // additive const in f-row
    const float shiftc = odd ? SC1 * T2L : 0.0f; // pre-scaled tanh shift
    const float cKn    = (q == 2) ? K0 : (q == 3) ? K1 : 0.0f;
    const float wmask  = hi ? 0.0f : 1.0f;
    const float cwc    = (q == 1) ? Bcf : 0.0f;
    // phi row coeffs: h_q = am + a0*V + a1*rot1 + a2*rot2 + a3*rot3
    const float am = (q == 0) ? Mp[0] : (q == 1) ? Mp[1] : (q == 2) ? Mp[2] : Mp[3];
    const float a0 = (q == 0) ? A00 : (q == 1) ? A11 : (q == 2) ? A22 : A33;
    const float a1 = (q == 0) ? A01 : (q == 1) ? A12 : (q == 2) ? A23 : A03;
    const float a2 = (q == 0) ? A02 : (q == 1) ? A13 : (q == 2) ? A02 : A13;
    const float a3 = (q == 0) ? A03 : (q == 1) ? A01 : (q == 2) ? A12 : A23;

    const float* rw = w + (size_t)b * (2 * NSTEP) + (size_t)(q & 1) * NSTEP;
    const float w_0 = rw[0], w_1 = rw[1], w_T = rw[2046];

    // prologue tanh(1) and tanh(H/2)
    const float th1 = 1.0f - 2.0f * frcp(fexp2(T2L) + 1.0f);
    const float thS = 1.0f - 2.0f * frcp(fexp2(SC1 * T2L) + 1.0f);

    // ---- t = 0 (delta=1, xhat0=(1,0), u0=K0) -> state entering step t=1 ----
    // lanes 0,1 hold x(t=1); lanes 2,3 hold xhat(t=1) = x0 = (1,0)
    float St = (q == 0) ? (Acf + Hc * SC1 + Hc * K0 + w_0)
             : (q == 1) ? (Bcf - Hc * th1 + HH * K0 + w_0)
             : (q == 2) ? 1.0f : 0.0f;
    // swapped xhat-tanh entering step 1: lane2 needs S(xh2_0)=tanh(H/2), lane3 tanh(xh1_0)=tanh(1)
    float TPin = (q == 2) ? thS : (q == 3) ? th1 : 0.0f;
    float U   = K0;
    float SXX = (q == 0) ? 1.0f : 0.0f;   // lane0: sum x1^2 (incl t=0), lane1: sum x2^2
    float SXY = 0.0f;                     // lane0: sum x1*x2
    float SD  = 1.0f;                     // sum deltas (t=0 term = 1)

    auto step = [&](float wi, bool acc) {
        // F = f(xhat_prev, u_prev) component (valid on lanes 2,3)
        const float cc = __builtin_fmaf(cUf, U, c0f);
        const float F  = __builtin_fmaf(Acf, St, __builtin_fmaf(cTf, TPin, cc));
        // rx component: lanes 0,1 -> x ; lanes 2,3 -> F
        const float V  = hi ? F : St;
        // quad gather for phi row
        const float r1 = qperm<ROT1>(V);
        const float r2 = qperm<XOR2>(V);
        const float r3 = qperm<ROT3>(V);
        float h = __builtin_fmaf(a0, V, am);
        h = __builtin_fmaf(a1, r1, h);
        h = __builtin_fmaf(a2, r2, h);
        h = __builtin_fmaf(a3, r3, h);
        const float part = V * h;
        float ps = part + qperm<XOR1>(part);
        ps = ps + qperm<XOR2>(ps);
        // sigmoid (duplicated on quad)
        const float dE = fexp2(__builtin_fmaf(ps, -L2E, sigBias));
        const float delta = frcp(1.0f + dE);
        // own tanh at V (lanes 0,1: x-side; lanes 2,3: at F, Taylor base)
        const float tE = fexp2(__builtin_fmaf(T2L, V, shiftc));
        const float th = __builtin_fmaf(-2.0f, frcp(tE + 1.0f), 1.0f);
        const float s  = __builtin_fmaf(-th, th, 1.0f);   // sech^2
        // u = K.F + delta * K.(X - F); both reduces hide under sigmoid latency
        const float Dl = r2 - F;                  // lanes 2,3: x_partner - F
        const float tF = cKn * F;
        const float tD = cKn * Dl;
        float kF = tF + qperm<XOR1>(tF); kF = kF + qperm<XOR2>(kF);
        float kD = tD + qperm<XOR1>(tD); kD = kD + qperm<XOR2>(kD);
        const float un = __builtin_fmaf(delta, kD, kF);
        if (acc) {
            SXX = __builtin_fmaf(V, V, SXX);
            SXY = __builtin_fmaf(V, r1, SXY);
            SD += delta;
        }
        // xhat update + Taylor-corrected tanh(NH) = tanh(F + d)
        const float d   = delta * Dl;
        const float NH  = F + d;
        const float c2t = __builtin_fmaf(-d, th, 1.0f);
        const float c1t = d * s;
        const float th_eff = __builtin_fmaf(c1t, c2t, th);
        const float TPx = qperm<XOR1>(th);        // lanes 0,1: partner x-tanh
        TPin = qperm<XOR1>(th_eff);               // lanes 2,3: partner xhat-tanh
        // x update (lanes 0,1)
        const float cwv = __builtin_fmaf(wi, wmask, cwc);
        const float Rr  = __builtin_fmaf(Acf, St, __builtin_fmaf(cTf, TPx, cwv));
        const float Xn  = __builtin_fmaf(cUf, un, Rr);
        St = hi ? NH : Xn;
        U  = un;
    };

    // t = 1
    step(w_1, true);

    // t = 2 .. 2045: 511 groups of 4; unroll-2 role-swapped double buffer.
    float c0 = rw[2], c1 = rw[3], c2 = rw[4], c3 = rw[5];
    const float* p = rw + 6;
    for (int k = 0; k < 255; ++k) {
        const float n0 = p[0], n1 = p[1], n2 = p[2], n3 = p[3];
        step(c0, true); step(c1, true); step(c2, true); step(c3, true);
        c0 = p[4]; c1 = p[5]; c2 = p[6]; c3 = p[7];
        step(n0, true); step(n1, true); step(n2, true); step(n3, true);
        p += 8;
    }
    step(c0, true); step(c1, true); step(c2, true); step(c3, true);

    // t = 2046: final step, no stage accumulation
    step(w_T, false);

    // epilogue: out = (Sx1x1+Sx2x2) + (K'SK quadratic) + SD + 10*|x_T|^2
    const float xx    = St * St;              // x_T^2 components on lanes 0,1
    const float sxx_p = qperm<XOR1>(SXX);     // lane0 <- lane1's sum x2^2
    const float xx_s  = xx + qperm<XOR1>(xx); // lane0: x1_T^2 + x2_T^2
    const float suu   = K0 * K0 * SXX + 2.0f * K0 * K1 * SXY + K1 * K1 * sxx_p;
    const float res   = (SXX + sxx_p) + suu + SD + 10.0f * xx_s;
    if (q == 0) out[b] = res;
}

extern "C" void kernel_launch(void* const* d_in, const int* in_sizes, int n_in,
                              void* d_out, int out_size, void* d_ws, size_t ws_size,
                              hipStream_t stream) {
    const float* w  = (const float*)d_in[0];
    const float* K  = (const float*)d_in[1];
    const float* L  = (const float*)d_in[2];
    const float* M  = (const float*)d_in[3];
    const float* Mo = (const float*)d_in[4];
    float* out = (float*)d_out;
    cstr_kernel<<<dim3(4 * NB / 64), dim3(64), 0, stream>>>(w, K, L, M, Mo, out);
}